// Round 1
// baseline (83.270 us; speedup 1.0000x reference)
//
#include <hip/hip_runtime.h>
#include <math.h>

#define KG_B 16384
#define KG_D 128

// One wave (64 lanes) per batch element. Each lane owns output columns
// (2*lane, 2*lane+1). W row slices loaded as float2 (coalesced, 512B/wave),
// reused across all three vec-mat products (h, pos_t, neg_t).
__global__ __launch_bounds__(64) void kg_elem_kernel(
    const float* __restrict__ ent,   // [300000,128] entity_user_embed
    const float* __restrict__ rel,   // [24,128]     relation_embed
    const float* __restrict__ M,     // [24,128,128] trans_M
    const int*   __restrict__ h,
    const int*   __restrict__ r,
    const int*   __restrict__ pt,
    const int*   __restrict__ nt,
    float* __restrict__ ws)          // [KG_B] per-element terms
{
    const int b    = blockIdx.x;
    const int lane = threadIdx.x;

    __shared__ float svh[KG_D];
    __shared__ float svp[KG_D];
    __shared__ float svn[KG_D];
    __shared__ float svr[KG_D];

    const int hb = h[b];
    const int rb = r[b];
    const int pb = pt[b];
    const int nb = nt[b];

    // Stage gathered vectors in LDS (2 floats per lane per vector).
    {
        const float2 th = *(const float2*)(ent + (size_t)hb * KG_D + 2 * lane);
        const float2 tp = *(const float2*)(ent + (size_t)pb * KG_D + 2 * lane);
        const float2 tn = *(const float2*)(ent + (size_t)nb * KG_D + 2 * lane);
        const float2 tr = *(const float2*)(rel + (size_t)rb * KG_D + 2 * lane);
        svh[2 * lane] = th.x; svh[2 * lane + 1] = th.y;
        svp[2 * lane] = tp.x; svp[2 * lane + 1] = tp.y;
        svn[2 * lane] = tn.x; svn[2 * lane + 1] = tn.y;
        svr[2 * lane] = tr.x; svr[2 * lane + 1] = tr.y;
    }
    __syncthreads();

    const float* __restrict__ Wr = M + (size_t)rb * KG_D * KG_D;

    float ahx = 0.f, ahy = 0.f;   // r_mul_h columns (2*lane, 2*lane+1)
    float apx = 0.f, apy = 0.f;   // r_mul_pos_t
    float anx = 0.f, any_ = 0.f;  // r_mul_neg_t

#pragma unroll 8
    for (int e = 0; e < KG_D; ++e) {
        const float2 w = *(const float2*)(Wr + (size_t)e * KG_D + 2 * lane);
        const float vh = svh[e];
        const float vp = svp[e];
        const float vn = svn[e];
        ahx = fmaf(vh, w.x, ahx); ahy = fmaf(vh, w.y, ahy);
        apx = fmaf(vp, w.x, apx); apy = fmaf(vp, w.y, apy);
        anx = fmaf(vn, w.x, anx); any_ = fmaf(vn, w.y, any_);
    }

    const float r0 = svr[2 * lane];
    const float r1 = svr[2 * lane + 1];

    const float dp0 = ahx + r0 - apx;
    const float dp1 = ahy + r1 - apy;
    const float dn0 = ahx + r0 - anx;
    const float dn1 = ahy + r1 - any_;

    float ps  = dp0 * dp0 + dp1 * dp1;                  // pos_score partial
    float ns  = dn0 * dn0 + dn1 * dn1;                  // neg_score partial
    float ssq = ahx * ahx + ahy * ahy                    // ||r_mul_h||^2
              + apx * apx + apy * apy                    // ||r_mul_pos_t||^2
              + anx * anx + any_ * any_                  // ||r_mul_neg_t||^2
              + r0 * r0 + r1 * r1;                       // ||r_embed||^2

    // 64-lane butterfly reduction
    for (int off = 32; off > 0; off >>= 1) {
        ps  += __shfl_down(ps, off);
        ns  += __shfl_down(ns, off);
        ssq += __shfl_down(ssq, off);
    }

    if (lane == 0) {
        // -log_sigmoid(neg - pos) = softplus(pos - neg)
        const float x  = ps - ns;
        const float kg = fmaxf(x, 0.f) + log1pf(expf(-fabsf(x)));
        ws[b] = kg + 1e-5f * 0.5f * ssq;
    }
}

// Deterministic single-block reduction: fixed per-thread strided sums then
// fixed LDS tree. Fully overwrites d_out[0] (poison-safe), no atomics.
__global__ __launch_bounds__(256) void kg_reduce_kernel(
    const float* __restrict__ ws, float* __restrict__ out)
{
    __shared__ float s[256];
    const int t = threadIdx.x;
    float acc = 0.f;
    for (int i = t; i < KG_B; i += 256) acc += ws[i];
    s[t] = acc;
    __syncthreads();
    for (int off = 128; off > 0; off >>= 1) {
        if (t < off) s[t] += s[t + off];
        __syncthreads();
    }
    if (t == 0) out[0] = s[0] * (1.0f / (float)KG_B);
}

extern "C" void kernel_launch(void* const* d_in, const int* in_sizes, int n_in,
                              void* d_out, int out_size, void* d_ws, size_t ws_size,
                              hipStream_t stream) {
    const float* ent = (const float*)d_in[0];  // entity_user_embed [300000,128]
    const float* rel = (const float*)d_in[1];  // relation_embed   [24,128]
    const float* M   = (const float*)d_in[2];  // trans_M          [24,128,128]
    const int*   h   = (const int*)d_in[3];
    const int*   r   = (const int*)d_in[4];
    const int*   pt  = (const int*)d_in[5];
    const int*   nt  = (const int*)d_in[6];

    float* ws  = (float*)d_ws;   // KG_B floats of scratch
    float* out = (float*)d_out;  // 1 float

    kg_elem_kernel<<<KG_B, 64, 0, stream>>>(ent, rel, M, h, r, pt, nt, ws);
    kg_reduce_kernel<<<1, 256, 0, stream>>>(ws, out);
}